// Round 8
// baseline (857.527 us; speedup 1.0000x reference)
//
#include <hip/hip_runtime.h>
#include <math.h>

// Problem constants: N=16, L=4096, C=256, NC=512, NR=1, WS=1
typedef _Float16 half8 __attribute__((ext_vector_type(8)));
typedef float    f32x4 __attribute__((ext_vector_type(4)));

// ws layout (byte offsets)
constexpr size_t B_WX2   = 0;                       // Wx split-f16, interleaved hi|lo per 8k (256KB)
constexpr size_t B_WY2   = 262144;                  // Wy same (256KB)
constexpr size_t B_M2    = 524288;                  // means same (512KB)
constexpr size_t B_INVR1 = 1048576;                 // 16x256 f32, clamp 1e-12
constexpr size_t B_INVR2 = 1064960;                 // 16x256 f32, clamp 5e-5
constexpr size_t B_S0    = 1081344;                 // 16x4096 f32
constexpr size_t B_S1    = 1343488;
constexpr size_t B_S2    = 1605632;
constexpr size_t B_BS    = 1867776;
constexpr size_t B_MX    = 2129920;                 // 16 f32
constexpr size_t B_Z     = 2129984;                 // 16 f32
constexpr size_t B_R2    = 2130048;                 // 16x256 f64
constexpr size_t B_CODES = 2162816;                 // 16x4096 i32
constexpr size_t B_IDX   = 2424960;                 // sorted->orig
constexpr size_t B_US    = 2687104;                 // orig->sorted rank
constexpr size_t B_XE    = 4194304;                 // x_embed 16x4096x256 f32 (64MB)
constexpr size_t B_YE    = 71303168;
constexpr size_t WS_NEED = 138412032;

// Split Wx/Wy/means into f16 hi/lo, stored interleaved: for (row r, k-octet k8)
// hi8 at half8-index (r*32+k8)*2, lo8 at +1 — one 32B cacheline chunk per triple-MFMA.
__global__ void k_prep(const float* __restrict__ Wx, const float* __restrict__ Wy,
                       const float* __restrict__ means,
                       _Float16* __restrict__ WX2, _Float16* __restrict__ WY2,
                       _Float16* __restrict__ M2)
{
    int t = blockIdx.x*256 + threadIdx.x;
    if (t < 65536) {
        int r = t >> 8, c = t & 255, k8 = c >> 3, e = c & 7;
        size_t base = ((size_t)(r*32 + k8)*2)*8 + e;
        float a = Wx[t]; _Float16 ha = (_Float16)a;
        WX2[base] = ha; WX2[base + 8] = (_Float16)(a - (float)ha);
        float b = Wy[t]; _Float16 hb = (_Float16)b;
        WY2[base] = hb; WY2[base + 8] = (_Float16)(b - (float)hb);
    }
    if (t < 131072) {
        int r = t >> 8, c = t & 255, k8 = c >> 3, e = c & 7;
        size_t base = ((size_t)(r*32 + k8)*2)*8 + e;
        float m = means[t]; _Float16 hm = (_Float16)m;
        M2[base] = hm; M2[base + 8] = (_Float16)(m - (float)hm);
    }
}

// Fused GEMM (x @ W^T + b) + LayerNorm + ReLU via split-f16 3-pass MFMA.
// 4 waves/block; wave w: 16 rows x 64 cols (4 acc tiles -> low VGPR, high occupancy).
// mfma_f32_16x16x32_f16: A lane: row=l&15 ; B lane: col=l&15 ; D lane: col=l&15, row=4*(l>>4)+v
__global__ __launch_bounds__(256, 4) void k_embed_mfma(
    const float* __restrict__ xin, const _Float16* __restrict__ W2,
    const float* __restrict__ bias, const float* __restrict__ gg,
    const float* __restrict__ be, float* __restrict__ outp,
    double* __restrict__ r2, int do_r2)
{
    __shared__ float lnA[4][16];
    __shared__ float lnB[4][16];
    const int tid = threadIdx.x;
    const int l = tid & 63, w = tid >> 6;
    const int row16 = l & 15, kgrp = l >> 4;
    const int cb = w * 64;
    const size_t row0 = (size_t)blockIdx.x * 16;
    f32x4 acc[4];
    #pragma unroll
    for (int t = 0; t < 4; ++t) acc[t] = (f32x4){0.f, 0.f, 0.f, 0.f};

    const half8* W8 = (const half8*)W2;
    #pragma unroll
    for (int ks = 0; ks < 8; ++ks) {
        const int kb = ks*32 + kgrp*8;
        const float* xp = xin + (row0 + row16)*256 + kb;
        float4 xa = *(const float4*)xp;
        float4 xb = *(const float4*)(xp + 4);
        float xv[8] = {xa.x, xa.y, xa.z, xa.w, xb.x, xb.y, xb.z, xb.w};
        half8 ah, al;
        #pragma unroll
        for (int e = 0; e < 8; ++e) {
            _Float16 h = (_Float16)xv[e];
            ah[e] = h;
            al[e] = (_Float16)(xv[e] - (float)h);
        }
        #pragma unroll
        for (int t = 0; t < 4; ++t) {
            const half8* bp = W8 + ((size_t)(cb + t*16 + row16)*32 + (kb >> 3))*2;
            half8 bh = bp[0];
            half8 bl = bp[1];
            acc[t] = __builtin_amdgcn_mfma_f32_16x16x32_f16(ah, bh, acc[t], 0, 0, 0);
            acc[t] = __builtin_amdgcn_mfma_f32_16x16x32_f16(ah, bl, acc[t], 0, 0, 0);
            acc[t] = __builtin_amdgcn_mfma_f32_16x16x32_f16(al, bh, acc[t], 0, 0, 0);
        }
    }
    // epilogue: lane holds rows 4*kgrp+v, cols cb+t*16+row16
    float bias_t[4], g_t[4], be_t[4];
    #pragma unroll
    for (int t = 0; t < 4; ++t) {
        int c = cb + t*16 + row16;
        bias_t[t] = bias[c]; g_t[t] = gg[c]; be_t[t] = be[c];
    }
    #pragma unroll
    for (int t = 0; t < 4; ++t) {
        acc[t][0] += bias_t[t]; acc[t][1] += bias_t[t];
        acc[t][2] += bias_t[t]; acc[t][3] += bias_t[t];
    }
    float sum[4] = {0.f, 0.f, 0.f, 0.f};
    #pragma unroll
    for (int t = 0; t < 4; ++t) {
        sum[0] += acc[t][0]; sum[1] += acc[t][1];
        sum[2] += acc[t][2]; sum[3] += acc[t][3];
    }
    #pragma unroll
    for (int v = 0; v < 4; ++v) {
        #pragma unroll
        for (int off = 1; off < 16; off <<= 1) sum[v] += __shfl_xor(sum[v], off, 64);
    }
    if (row16 == 0) {
        #pragma unroll
        for (int v = 0; v < 4; ++v) lnA[w][kgrp*4 + v] = sum[v];
    }
    __syncthreads();
    float mu[4];
    #pragma unroll
    for (int v = 0; v < 4; ++v) {
        int r = kgrp*4 + v;
        mu[v] = (lnA[0][r] + lnA[1][r] + lnA[2][r] + lnA[3][r]) * (1.0f/256.0f);
    }
    float ss[4] = {0.f, 0.f, 0.f, 0.f};
    #pragma unroll
    for (int t = 0; t < 4; ++t) {
        #pragma unroll
        for (int v = 0; v < 4; ++v) { float d = acc[t][v] - mu[v]; ss[v] += d*d; }
    }
    #pragma unroll
    for (int v = 0; v < 4; ++v) {
        #pragma unroll
        for (int off = 1; off < 16; off <<= 1) ss[v] += __shfl_xor(ss[v], off, 64);
    }
    if (row16 == 0) {
        #pragma unroll
        for (int v = 0; v < 4; ++v) lnB[w][kgrp*4 + v] = ss[v];
    }
    __syncthreads();
    float istd[4];
    #pragma unroll
    for (int v = 0; v < 4; ++v) {
        int r = kgrp*4 + v;
        float tot = lnB[0][r] + lnB[1][r] + lnB[2][r] + lnB[3][r];
        istd[v] = 1.0f / sqrtf(tot*(1.0f/256.0f) + 1e-5f);
    }
    const int n = (int)(row0 >> 12);
    #pragma unroll
    for (int t = 0; t < 4; ++t) {
        float sq = 0.f;
        #pragma unroll
        for (int v = 0; v < 4; ++v) {
            float o = fmaxf((acc[t][v] - mu[v])*istd[v]*g_t[t] + be_t[t], 0.f);
            outp[(row0 + kgrp*4 + v)*256 + cb + t*16 + row16] = o;
            sq += o*o;
        }
        if (do_r2) {
            sq += __shfl_xor(sq, 16, 64);
            sq += __shfl_xor(sq, 32, 64);
            if (kgrp == 0) atomicAdd(&r2[n*256 + cb + t*16 + row16], (double)sq);
        }
    }
}

__global__ void k_finish(const double* __restrict__ r2,
                         float* __restrict__ invr1, float* __restrict__ invr2)
{
    int t = blockIdx.x*256 + threadIdx.x;   // 4096
    float r = (float)sqrt(r2[t]);
    invr1[t] = 1.0f / fmaxf(r, 1e-12f);
    invr2[t] = 1.0f / fmaxf(r, 5e-5f);
}

// dists = (x*invr1) @ meansT via split-f16 MFMA + in-register argmax (first-max wins).
// 8 waves/block; wave w: 16 rows x 64 cols of the 512.
__global__ __launch_bounds__(512, 4) void k_dists_mfma(
    const float* __restrict__ X, const _Float16* __restrict__ M2,
    const float* __restrict__ invr, int* __restrict__ codes)
{
    __shared__ float wbv[8][16];
    __shared__ int   wbi[8][16];
    const int tid = threadIdx.x, l = tid & 63, w = tid >> 6;
    const int row16 = l & 15, kgrp = l >> 4;
    const int cb = w * 64;
    const size_t row0 = (size_t)blockIdx.x * 16;
    const int n = (int)(row0 >> 12);
    f32x4 acc[4];
    #pragma unroll
    for (int t = 0; t < 4; ++t) acc[t] = (f32x4){0.f, 0.f, 0.f, 0.f};

    const half8* M8 = (const half8*)M2;
    #pragma unroll
    for (int ks = 0; ks < 8; ++ks) {
        const int kb = ks*32 + kgrp*8;
        const float* xp = X + (row0 + row16)*256 + kb;
        float4 xa = *(const float4*)xp;
        float4 xb = *(const float4*)(xp + 4);
        const float* ip = invr + n*256 + kb;
        float4 ia = *(const float4*)ip;
        float4 ib = *(const float4*)(ip + 4);
        float xv[8] = {xa.x*ia.x, xa.y*ia.y, xa.z*ia.z, xa.w*ia.w,
                       xb.x*ib.x, xb.y*ib.y, xb.z*ib.z, xb.w*ib.w};
        half8 ah, al;
        #pragma unroll
        for (int e = 0; e < 8; ++e) {
            _Float16 h = (_Float16)xv[e];
            ah[e] = h;
            al[e] = (_Float16)(xv[e] - (float)h);
        }
        #pragma unroll
        for (int t = 0; t < 4; ++t) {
            const half8* bp = M8 + ((size_t)(cb + t*16 + row16)*32 + (kb >> 3))*2;
            half8 bh = bp[0];
            half8 bl = bp[1];
            acc[t] = __builtin_amdgcn_mfma_f32_16x16x32_f16(ah, bh, acc[t], 0, 0, 0);
            acc[t] = __builtin_amdgcn_mfma_f32_16x16x32_f16(ah, bl, acc[t], 0, 0, 0);
            acc[t] = __builtin_amdgcn_mfma_f32_16x16x32_f16(al, bh, acc[t], 0, 0, 0);
        }
    }
    // per-row argmax over this wave's 64 cols (cols ascend with t: '>' keeps first)
    float bv[4]; int bi[4];
    #pragma unroll
    for (int v = 0; v < 4; ++v) { bv[v] = -3.0e38f; bi[v] = 0x7fffffff; }
    #pragma unroll
    for (int t = 0; t < 4; ++t) {
        int c = cb + t*16 + row16;
        #pragma unroll
        for (int v = 0; v < 4; ++v) {
            float val = acc[t][v];
            if (val > bv[v]) { bv[v] = val; bi[v] = c; }
        }
    }
    #pragma unroll
    for (int v = 0; v < 4; ++v) {
        #pragma unroll
        for (int off = 1; off < 16; off <<= 1) {
            float ov = __shfl_xor(bv[v], off, 64);
            int   oi = __shfl_xor(bi[v], off, 64);
            if (ov > bv[v] || (ov == bv[v] && oi < bi[v])) { bv[v] = ov; bi[v] = oi; }
        }
        if (row16 == 0) { wbv[w][kgrp*4 + v] = bv[v]; wbi[w][kgrp*4 + v] = bi[v]; }
    }
    __syncthreads();
    if (tid < 16) {
        float best = wbv[0][tid]; int besti = wbi[0][tid];
        #pragma unroll
        for (int q = 1; q < 8; ++q) {
            float v = wbv[q][tid]; int i = wbi[q][tid];
            if (v > best || (v == best && i < besti)) { best = v; besti = i; }
        }
        codes[row0 + tid] = besti;
    }
}

// Per-batch stable counting sort of codes in [0,512).
__global__ __launch_bounds__(256) void k_sort(const int* __restrict__ codes,
                                              int* __restrict__ sidx, int* __restrict__ us)
{
    __shared__ int hist[512];
    __shared__ int part[16];
    __shared__ int chunk[256];
    const int n = blockIdx.x, tid = threadIdx.x;
    hist[tid] = 0; hist[tid + 256] = 0;
    __syncthreads();
    const int* cds = codes + n*4096;
    for (int i = 0; i < 16; ++i) atomicAdd(&hist[cds[i*256 + tid]], 1);
    __syncthreads();
    if (tid < 16) { int s = 0; for (int b = 0; b < 32; ++b) s += hist[tid*32 + b]; part[tid] = s; }
    __syncthreads();
    if (tid == 0) { int run = 0; for (int t = 0; t < 16; ++t) { int tmp = part[t]; part[t] = run; run += tmp; } }
    __syncthreads();
    if (tid < 16) { int base = part[tid];
        for (int b = 0; b < 32; ++b) { int tmp = hist[tid*32 + b]; hist[tid*32 + b] = base; base += tmp; } }
    __syncthreads();
    for (int i = 0; i < 16; ++i) {
        int lix = i*256 + tid;
        int c = cds[lix];
        chunk[tid] = c;
        __syncthreads();
        int rank = hist[c];
        for (int u = 0; u < 256; ++u) {
            if (u < tid && chunk[u] == c) ++rank;
        }
        sidx[n*4096 + rank] = lix;
        us[n*4096 + lix] = rank;
        __syncthreads();
        atomicAdd(&hist[c], 1);
        __syncthreads();
    }
}

// One wave per sorted position k: the 3 neighbor scores + logsumexp.
__global__ __launch_bounds__(256) void k_bs(
    const float* __restrict__ X, const float* __restrict__ invr,
    const int* __restrict__ sidx,
    float* __restrict__ S0, float* __restrict__ S1,
    float* __restrict__ S2, float* __restrict__ BS)
{
    const int gw = blockIdx.x*4 + (threadIdx.x >> 6);
    const int lane = threadIdx.x & 63;
    const int n = gw >> 12, k = gw & 4095;
    const int base = n*4096;
    const int i0 = sidx[base + k];
    const int im = sidx[base + ((k + 4095) & 4095)];
    const int ip = sidx[base + ((k + 1) & 4095)];
    const float4* x0 = (const float4*)(X + ((size_t)base + i0)*256);
    const float4* xm = (const float4*)(X + ((size_t)base + im)*256);
    const float4* xp = (const float4*)(X + ((size_t)base + ip)*256);
    const float4* ir4 = (const float4*)(invr + n*256);
    float4 a = x0[lane], m_ = xm[lane], p_ = xp[lane], ir = ir4[lane];
    float ax = a.x*ir.x, ay = a.y*ir.y, az = a.z*ir.z, aw = a.w*ir.w;
    float p0 = ax*a.x + ay*a.y + az*a.z + aw*a.w;
    float p1 = ax*m_.x + ay*m_.y + az*m_.z + aw*m_.w;
    float p2 = ax*p_.x + ay*p_.y + az*p_.z + aw*p_.w;
    #pragma unroll
    for (int off = 32; off > 0; off >>= 1) {
        p0 += __shfl_xor(p0, off, 64);
        p1 += __shfl_xor(p1, off, 64);
        p2 += __shfl_xor(p2, off, 64);
    }
    if (lane == 0) {
        float m = fmaxf(p0, fmaxf(p1, p2));
        float bs = m + logf(expf(p0 - m) + expf(p1 - m) + expf(p2 - m));
        S0[gw] = p0; S1[gw] = p1; S2[gw] = p2; BS[gw] = bs;
    }
}

// Per-batch max & sum(exp) of bucket scores.
__global__ __launch_bounds__(256) void k_red(const float* __restrict__ BS,
                                             float* __restrict__ MX, float* __restrict__ Zs)
{
    __shared__ float red[256];
    const int n = blockIdx.x, tid = threadIdx.x;
    const float* b = BS + n*4096;
    float mx = -3.0e38f;
    for (int i = 0; i < 16; ++i) mx = fmaxf(mx, b[i*256 + tid]);
    red[tid] = mx; __syncthreads();
    for (int s = 128; s > 0; s >>= 1) { if (tid < s) red[tid] = fmaxf(red[tid], red[tid + s]); __syncthreads(); }
    float gmx = red[0];
    __syncthreads();
    float sum = 0.f;
    for (int i = 0; i < 16; ++i) sum += expf(b[i*256 + tid] - gmx);
    red[tid] = sum; __syncthreads();
    for (int s = 128; s > 0; s >>= 1) { if (tid < s) red[tid] += red[tid + s]; __syncthreads(); }
    if (tid == 0) { MX[n] = gmx; Zs[n] = red[0]; }
}

// One wave per original position p: gather ys rows, softmax-3 combine, global prob, blend.
__global__ __launch_bounds__(256) void k_final(
    const float* __restrict__ inp, const float* __restrict__ Y,
    const int* __restrict__ sidx, const int* __restrict__ us,
    const float* __restrict__ S0, const float* __restrict__ S1,
    const float* __restrict__ S2, const float* __restrict__ BS,
    const float* __restrict__ MX, const float* __restrict__ Zs,
    const float* __restrict__ alpha_p, float* __restrict__ outp)
{
    const int gw = blockIdx.x*4 + (threadIdx.x >> 6);
    const int lane = threadIdx.x & 63;
    const int n = gw >> 12, p = gw & 4095;
    const int base = n*4096;
    const int k = us[base + p];
    const int i0 = sidx[base + k];
    const int im = sidx[base + ((k + 4095) & 4095)];
    const int ip = sidx[base + ((k + 1) & 4095)];
    const int kk = base + k;
    float bs = BS[kk];
    float w0 = expf(S0[kk] - bs), w1 = expf(S1[kk] - bs), w2 = expf(S2[kk] - bs);
    float alpha = alpha_p[0];
    float coef = (1.0f - alpha) * expf(bs - MX[n]) / Zs[n];
    const float4* y0 = (const float4*)(Y + ((size_t)base + i0)*256);
    const float4* ym = (const float4*)(Y + ((size_t)base + im)*256);
    const float4* yp = (const float4*)(Y + ((size_t)base + ip)*256);
    const float4* iv = (const float4*)(inp + ((size_t)base + p)*256);
    float4 A = y0[lane], Bv = ym[lane], Cv = yp[lane], I = iv[lane];
    float4 o;
    o.x = alpha*I.x + coef*(w0*A.x + w1*Bv.x + w2*Cv.x);
    o.y = alpha*I.y + coef*(w0*A.y + w1*Bv.y + w2*Cv.y);
    o.z = alpha*I.z + coef*(w0*A.z + w1*Bv.z + w2*Cv.z);
    o.w = alpha*I.w + coef*(w0*A.w + w1*Bv.w + w2*Cv.w);
    ((float4*)(outp + ((size_t)base + p)*256))[lane] = o;
}

extern "C" void kernel_launch(void* const* d_in, const int* in_sizes, int n_in,
                              void* d_out, int out_size, void* d_ws, size_t ws_size,
                              hipStream_t stream)
{
    const float* inputs = (const float*)d_in[0];
    const float* Wx  = (const float*)d_in[1];
    const float* bx  = (const float*)d_in[2];
    const float* gx  = (const float*)d_in[3];
    const float* bex = (const float*)d_in[4];
    const float* Wy  = (const float*)d_in[5];
    const float* by  = (const float*)d_in[6];
    const float* gy  = (const float*)d_in[7];
    const float* bey = (const float*)d_in[8];
    const float* means = (const float*)d_in[9];
    const float* alpha = (const float*)d_in[10];

    if (ws_size < WS_NEED) return;  // loud failure (output stays poisoned)

    char* ws = (char*)d_ws;
    _Float16* WX2 = (_Float16*)(ws + B_WX2);
    _Float16* WY2 = (_Float16*)(ws + B_WY2);
    _Float16* M2  = (_Float16*)(ws + B_M2);
    float*  invr1 = (float*)(ws + B_INVR1);
    float*  invr2 = (float*)(ws + B_INVR2);
    float*  S0    = (float*)(ws + B_S0);
    float*  S1    = (float*)(ws + B_S1);
    float*  S2    = (float*)(ws + B_S2);
    float*  BSb   = (float*)(ws + B_BS);
    float*  MX    = (float*)(ws + B_MX);
    float*  Zs    = (float*)(ws + B_Z);
    double* r2    = (double*)(ws + B_R2);
    int*    codes = (int*)(ws + B_CODES);
    int*    sidx  = (int*)(ws + B_IDX);
    int*    us    = (int*)(ws + B_US);
    float*  XE    = (float*)(ws + B_XE);
    float*  YE    = (float*)(ws + B_YE);
    float*  outp  = (float*)d_out;

    hipMemsetAsync(r2, 0, 4096*8, stream);
    k_prep<<<512, 256, 0, stream>>>(Wx, Wy, means, WX2, WY2, M2);
    k_embed_mfma<<<4096, 256, 0, stream>>>(inputs, WX2, bx, gx, bex, XE, r2, 1);
    k_embed_mfma<<<4096, 256, 0, stream>>>(inputs, WY2, by, gy, bey, YE, r2, 0);
    k_finish<<<16, 256, 0, stream>>>(r2, invr1, invr2);
    k_dists_mfma<<<4096, 512, 0, stream>>>(XE, M2, invr1, codes);
    k_sort<<<16, 256, 0, stream>>>(codes, sidx, us);
    k_bs<<<16384, 256, 0, stream>>>(XE, invr2, sidx, S0, S1, S2, BSb);
    k_red<<<16, 256, 0, stream>>>(BSb, MX, Zs);
    k_final<<<16384, 256, 0, stream>>>(inputs, YE, sidx, us, S0, S1, S2, BSb, MX, Zs, alpha, outp);
}

// Round 9
// 455.329 us; speedup vs baseline: 1.8833x; 1.8833x over previous
//
#include <hip/hip_runtime.h>
#include <math.h>

// Problem constants: N=16, L=4096, C=256, NC=512, NR=1, WS=1
typedef _Float16 half8 __attribute__((ext_vector_type(8)));
typedef float    f32x4 __attribute__((ext_vector_type(4)));

// ws layout (byte offsets)
constexpr size_t B_WX2   = 0;                       // Wx split-f16 fragment-swizzled (256KB)
constexpr size_t B_WY2   = 262144;                  // Wy same (256KB)
constexpr size_t B_M2    = 524288;                  // means same (512KB)
constexpr size_t B_INVR1 = 1048576;                 // 16x256 f32, clamp 1e-12
constexpr size_t B_INVR2 = 1064960;                 // 16x256 f32, clamp 5e-5
constexpr size_t B_S0    = 1081344;                 // 16x4096 f32
constexpr size_t B_S1    = 1343488;
constexpr size_t B_S2    = 1605632;
constexpr size_t B_BS    = 1867776;
constexpr size_t B_MX    = 2129920;                 // 16 f32
constexpr size_t B_Z     = 2129984;                 // 16 f32
constexpr size_t B_R2    = 2130048;                 // 16x256 f64
constexpr size_t B_CODES = 2162816;                 // 16x4096 i32
constexpr size_t B_IDX   = 2424960;                 // sorted->orig
constexpr size_t B_US    = 2687104;                 // orig->sorted rank
constexpr size_t B_XE    = 4194304;                 // x_embed 16x4096x256 f32 (64MB)
constexpr size_t B_YE    = 71303168;
constexpr size_t WS_NEED = 138412032;

// Fragment-swizzle Wx/Wy/means into split-f16 hi/lo MFMA B-fragments:
// half index = ((ct*8 + ks)*2 + h)*512 + lane*8 + e
// value      = src[col=ct*16+(lane&15)][k=ks*32+(lane>>4)*8+e]
// -> a wave's B-load is 64 lanes x 16B CONTIGUOUS (perfectly coalesced).
__global__ void k_prep(const float* __restrict__ Wx, const float* __restrict__ Wy,
                       const float* __restrict__ means,
                       _Float16* __restrict__ WX2, _Float16* __restrict__ WY2,
                       _Float16* __restrict__ M2)
{
    int t = blockIdx.x*256 + threadIdx.x;
    int e = t & 7, l = (t >> 3) & 63, ks = (t >> 9) & 7, ct = t >> 12;
    int col = ct*16 + (l & 15);
    int k   = ks*32 + (l >> 4)*8 + e;
    if (t < 65536) {   // ct 0..15
        size_t dst = ((size_t)(ct*8 + ks)*2)*512 + l*8 + e;
        float a = Wx[col*256 + k]; _Float16 ha = (_Float16)a;
        WX2[dst] = ha; WX2[dst + 512] = (_Float16)(a - (float)ha);
        float b = Wy[col*256 + k]; _Float16 hb = (_Float16)b;
        WY2[dst] = hb; WY2[dst + 512] = (_Float16)(b - (float)hb);
    }
    if (t < 131072) {  // ct 0..31 (512 cols)
        size_t dst = ((size_t)(ct*8 + ks)*2)*512 + l*8 + e;
        float m = means[col*256 + k]; _Float16 hm = (_Float16)m;
        M2[dst] = hm; M2[dst + 512] = (_Float16)(m - (float)hm);
    }
}

// Fused GEMM (x @ W^T + b) + LayerNorm + ReLU via split-f16 3-pass MFMA.
// Block: 32 rows x 256 cols, 4 waves (wave w: 32r x 64c, 2 row-tiles x 4 col-tiles).
// A staged in LDS (coalesced HBM read, stride 260 to spread banks); B-frags coalesced global.
__global__ __launch_bounds__(256) void k_embed_mfma(
    const float* __restrict__ xin, const _Float16* __restrict__ W2,
    const float* __restrict__ bias, const float* __restrict__ gg,
    const float* __restrict__ be, float* __restrict__ outp,
    double* __restrict__ r2, int do_r2)
{
    __shared__ __align__(16) float tile[32*260];
    __shared__ float lnA[4][32];
    __shared__ float lnB[4][32];
    const int tid = threadIdx.x;
    const int l = tid & 63, w = tid >> 6;
    const int row16 = l & 15, kgrp = l >> 4;
    const int cb = w * 64;
    const size_t R0 = (size_t)blockIdx.x * 32;

    {   // stage A: 32 rows x 256 f32, coalesced
        const float4* src = (const float4*)(xin + R0*256);
        #pragma unroll
        for (int i = 0; i < 8; ++i) {
            int idx = i*256 + tid;           // float4 index in 32x256
            int r = idx >> 6, c4 = idx & 63;
            *(float4*)&tile[r*260 + c4*4] = src[idx];
        }
    }
    __syncthreads();

    f32x4 acc[2][4];
    #pragma unroll
    for (int rt = 0; rt < 2; ++rt)
        #pragma unroll
        for (int t = 0; t < 4; ++t) acc[rt][t] = (f32x4){0.f,0.f,0.f,0.f};

    const half8* W8 = (const half8*)W2;
    #pragma unroll
    for (int ks = 0; ks < 8; ++ks) {
        const int kb = ks*32 + kgrp*8;
        half8 ah[2], al[2];
        #pragma unroll
        for (int rt = 0; rt < 2; ++rt) {
            float4 a0 = *(const float4*)&tile[(rt*16 + row16)*260 + kb];
            float4 a1 = *(const float4*)&tile[(rt*16 + row16)*260 + kb + 4];
            float xv[8] = {a0.x,a0.y,a0.z,a0.w,a1.x,a1.y,a1.z,a1.w};
            #pragma unroll
            for (int e = 0; e < 8; ++e) {
                _Float16 h = (_Float16)xv[e];
                ah[rt][e] = h;
                al[rt][e] = (_Float16)(xv[e] - (float)h);
            }
        }
        #pragma unroll
        for (int t = 0; t < 4; ++t) {
            size_t fi = ((size_t)((w*4 + t)*8 + ks)*2)*64 + l;
            half8 bh = W8[fi];
            half8 bl = W8[fi + 64];
            acc[0][t] = __builtin_amdgcn_mfma_f32_16x16x32_f16(ah[0], bh, acc[0][t], 0,0,0);
            acc[0][t] = __builtin_amdgcn_mfma_f32_16x16x32_f16(ah[0], bl, acc[0][t], 0,0,0);
            acc[0][t] = __builtin_amdgcn_mfma_f32_16x16x32_f16(al[0], bh, acc[0][t], 0,0,0);
            acc[1][t] = __builtin_amdgcn_mfma_f32_16x16x32_f16(ah[1], bh, acc[1][t], 0,0,0);
            acc[1][t] = __builtin_amdgcn_mfma_f32_16x16x32_f16(ah[1], bl, acc[1][t], 0,0,0);
            acc[1][t] = __builtin_amdgcn_mfma_f32_16x16x32_f16(al[1], bh, acc[1][t], 0,0,0);
        }
    }

    // epilogue: lane holds rows rt*16 + 4*kgrp+v, cols cb + t*16 + row16
    float bias_t[4], g_t[4], be_t[4];
    #pragma unroll
    for (int t = 0; t < 4; ++t) {
        int c = cb + t*16 + row16;
        bias_t[t] = bias[c]; g_t[t] = gg[c]; be_t[t] = be[c];
    }
    #pragma unroll
    for (int rt = 0; rt < 2; ++rt)
        #pragma unroll
        for (int t = 0; t < 4; ++t) {
            acc[rt][t][0] += bias_t[t]; acc[rt][t][1] += bias_t[t];
            acc[rt][t][2] += bias_t[t]; acc[rt][t][3] += bias_t[t];
        }
    // LN mean
    #pragma unroll
    for (int rt = 0; rt < 2; ++rt) {
        float sum[4] = {0.f,0.f,0.f,0.f};
        #pragma unroll
        for (int t = 0; t < 4; ++t) {
            sum[0] += acc[rt][t][0]; sum[1] += acc[rt][t][1];
            sum[2] += acc[rt][t][2]; sum[3] += acc[rt][t][3];
        }
        #pragma unroll
        for (int v = 0; v < 4; ++v) {
            #pragma unroll
            for (int off = 1; off < 16; off <<= 1) sum[v] += __shfl_xor(sum[v], off, 64);
            if (row16 == 0) lnA[w][rt*16 + kgrp*4 + v] = sum[v];
        }
    }
    __syncthreads();
    float mu[2][4];
    #pragma unroll
    for (int rt = 0; rt < 2; ++rt)
        #pragma unroll
        for (int v = 0; v < 4; ++v) {
            int r = rt*16 + kgrp*4 + v;
            mu[rt][v] = (lnA[0][r] + lnA[1][r] + lnA[2][r] + lnA[3][r]) * (1.0f/256.0f);
        }
    // LN var
    #pragma unroll
    for (int rt = 0; rt < 2; ++rt) {
        float ss[4] = {0.f,0.f,0.f,0.f};
        #pragma unroll
        for (int t = 0; t < 4; ++t)
            #pragma unroll
            for (int v = 0; v < 4; ++v) { float d = acc[rt][t][v] - mu[rt][v]; ss[v] += d*d; }
        #pragma unroll
        for (int v = 0; v < 4; ++v) {
            #pragma unroll
            for (int off = 1; off < 16; off <<= 1) ss[v] += __shfl_xor(ss[v], off, 64);
            if (row16 == 0) lnB[w][rt*16 + kgrp*4 + v] = ss[v];
        }
    }
    __syncthreads();
    float istd[2][4];
    #pragma unroll
    for (int rt = 0; rt < 2; ++rt)
        #pragma unroll
        for (int v = 0; v < 4; ++v) {
            int r = rt*16 + kgrp*4 + v;
            float tot = lnB[0][r] + lnB[1][r] + lnB[2][r] + lnB[3][r];
            istd[rt][v] = 1.0f / sqrtf(tot*(1.0f/256.0f) + 1e-5f);
        }
    const int n = (int)(R0 >> 12);
    #pragma unroll
    for (int t = 0; t < 4; ++t) {
        float sq = 0.f;
        #pragma unroll
        for (int rt = 0; rt < 2; ++rt)
            #pragma unroll
            for (int v = 0; v < 4; ++v) {
                float o = fmaxf((acc[rt][t][v] - mu[rt][v])*istd[rt][v]*g_t[t] + be_t[t], 0.f);
                outp[(R0 + rt*16 + kgrp*4 + v)*256 + cb + t*16 + row16] = o;
                sq += o*o;
            }
        if (do_r2) {
            sq += __shfl_xor(sq, 16, 64);
            sq += __shfl_xor(sq, 32, 64);
            if (kgrp == 0) atomicAdd(&r2[n*256 + cb + t*16 + row16], (double)sq);
        }
    }
}

__global__ void k_finish(const double* __restrict__ r2,
                         float* __restrict__ invr1, float* __restrict__ invr2)
{
    int t = blockIdx.x*256 + threadIdx.x;   // 4096
    float r = (float)sqrt(r2[t]);
    invr1[t] = 1.0f / fmaxf(r, 1e-12f);
    invr2[t] = 1.0f / fmaxf(r, 5e-5f);
}

// dists = (x*invr1) @ meansT + in-register argmax (first-max wins).
// Block: 32 rows x 512 cols, 8 waves (wave w: 32r x 64c).
__global__ __launch_bounds__(512) void k_dists_mfma(
    const float* __restrict__ X, const _Float16* __restrict__ M2,
    const float* __restrict__ invr, int* __restrict__ codes)
{
    __shared__ __align__(16) float tile[32*260];
    __shared__ float wbv[8][32];
    __shared__ int   wbi[8][32];
    const int tid = threadIdx.x;
    const int l = tid & 63, w = tid >> 6;
    const int row16 = l & 15, kgrp = l >> 4;
    const int cb = w * 64;
    const size_t R0 = (size_t)blockIdx.x * 32;
    const int n = (int)(R0 >> 12);

    {   // stage A = x*invr, coalesced
        const float4* src = (const float4*)(X + R0*256);
        const float4* ir4 = (const float4*)(invr + n*256);
        #pragma unroll
        for (int i = 0; i < 4; ++i) {
            int idx = i*512 + tid;
            int r = idx >> 6, c4 = idx & 63;
            float4 x = src[idx];
            float4 ir = ir4[c4];
            x.x *= ir.x; x.y *= ir.y; x.z *= ir.z; x.w *= ir.w;
            *(float4*)&tile[r*260 + c4*4] = x;
        }
    }
    __syncthreads();

    f32x4 acc[2][4];
    #pragma unroll
    for (int rt = 0; rt < 2; ++rt)
        #pragma unroll
        for (int t = 0; t < 4; ++t) acc[rt][t] = (f32x4){0.f,0.f,0.f,0.f};

    const half8* M8 = (const half8*)M2;
    #pragma unroll
    for (int ks = 0; ks < 8; ++ks) {
        const int kb = ks*32 + kgrp*8;
        half8 ah[2], al[2];
        #pragma unroll
        for (int rt = 0; rt < 2; ++rt) {
            float4 a0 = *(const float4*)&tile[(rt*16 + row16)*260 + kb];
            float4 a1 = *(const float4*)&tile[(rt*16 + row16)*260 + kb + 4];
            float xv[8] = {a0.x,a0.y,a0.z,a0.w,a1.x,a1.y,a1.z,a1.w};
            #pragma unroll
            for (int e = 0; e < 8; ++e) {
                _Float16 h = (_Float16)xv[e];
                ah[rt][e] = h;
                al[rt][e] = (_Float16)(xv[e] - (float)h);
            }
        }
        #pragma unroll
        for (int t = 0; t < 4; ++t) {
            size_t fi = ((size_t)((w*4 + t)*8 + ks)*2)*64 + l;
            half8 bh = M8[fi];
            half8 bl = M8[fi + 64];
            acc[0][t] = __builtin_amdgcn_mfma_f32_16x16x32_f16(ah[0], bh, acc[0][t], 0,0,0);
            acc[0][t] = __builtin_amdgcn_mfma_f32_16x16x32_f16(ah[0], bl, acc[0][t], 0,0,0);
            acc[0][t] = __builtin_amdgcn_mfma_f32_16x16x32_f16(al[0], bh, acc[0][t], 0,0,0);
            acc[1][t] = __builtin_amdgcn_mfma_f32_16x16x32_f16(ah[1], bh, acc[1][t], 0,0,0);
            acc[1][t] = __builtin_amdgcn_mfma_f32_16x16x32_f16(ah[1], bl, acc[1][t], 0,0,0);
            acc[1][t] = __builtin_amdgcn_mfma_f32_16x16x32_f16(al[1], bh, acc[1][t], 0,0,0);
        }
    }

    // argmax: in-lane over t (cols ascend), cross-lane over row16, cross-wave ascending
    #pragma unroll
    for (int rt = 0; rt < 2; ++rt) {
        float bv[4]; int bi[4];
        #pragma unroll
        for (int v = 0; v < 4; ++v) { bv[v] = -3.0e38f; bi[v] = 0x7fffffff; }
        #pragma unroll
        for (int t = 0; t < 4; ++t) {
            int c = cb + t*16 + row16;
            #pragma unroll
            for (int v = 0; v < 4; ++v) {
                float val = acc[rt][t][v];
                if (val > bv[v]) { bv[v] = val; bi[v] = c; }
            }
        }
        #pragma unroll
        for (int v = 0; v < 4; ++v) {
            #pragma unroll
            for (int off = 1; off < 16; off <<= 1) {
                float ov = __shfl_xor(bv[v], off, 64);
                int   oi = __shfl_xor(bi[v], off, 64);
                if (ov > bv[v] || (ov == bv[v] && oi < bi[v])) { bv[v] = ov; bi[v] = oi; }
            }
            if (row16 == 0) { wbv[w][rt*16 + kgrp*4 + v] = bv[v]; wbi[w][rt*16 + kgrp*4 + v] = bi[v]; }
        }
    }
    __syncthreads();
    if (tid < 32) {
        float best = wbv[0][tid]; int besti = wbi[0][tid];
        #pragma unroll
        for (int q = 1; q < 8; ++q) {
            float v = wbv[q][tid]; int i = wbi[q][tid];
            if (v > best || (v == best && i < besti)) { best = v; besti = i; }
        }
        codes[R0 + tid] = besti;
    }
}

// Per-batch stable counting sort of codes in [0,512).
__global__ __launch_bounds__(256) void k_sort(const int* __restrict__ codes,
                                              int* __restrict__ sidx, int* __restrict__ us)
{
    __shared__ int hist[512];
    __shared__ int part[16];
    __shared__ int chunk[256];
    const int n = blockIdx.x, tid = threadIdx.x;
    hist[tid] = 0; hist[tid + 256] = 0;
    __syncthreads();
    const int* cds = codes + n*4096;
    for (int i = 0; i < 16; ++i) atomicAdd(&hist[cds[i*256 + tid]], 1);
    __syncthreads();
    if (tid < 16) { int s = 0; for (int b = 0; b < 32; ++b) s += hist[tid*32 + b]; part[tid] = s; }
    __syncthreads();
    if (tid == 0) { int run = 0; for (int t = 0; t < 16; ++t) { int tmp = part[t]; part[t] = run; run += tmp; } }
    __syncthreads();
    if (tid < 16) { int base = part[tid];
        for (int b = 0; b < 32; ++b) { int tmp = hist[tid*32 + b]; hist[tid*32 + b] = base; base += tmp; } }
    __syncthreads();
    for (int i = 0; i < 16; ++i) {
        int lix = i*256 + tid;
        int c = cds[lix];
        chunk[tid] = c;
        __syncthreads();
        int rank = hist[c];
        for (int u = 0; u < 256; ++u) {
            if (u < tid && chunk[u] == c) ++rank;
        }
        sidx[n*4096 + rank] = lix;
        us[n*4096 + lix] = rank;
        __syncthreads();
        atomicAdd(&hist[c], 1);
        __syncthreads();
    }
}

// One wave per sorted position k: the 3 neighbor scores + logsumexp.
__global__ __launch_bounds__(256) void k_bs(
    const float* __restrict__ X, const float* __restrict__ invr,
    const int* __restrict__ sidx,
    float* __restrict__ S0, float* __restrict__ S1,
    float* __restrict__ S2, float* __restrict__ BS)
{
    const int gw = blockIdx.x*4 + (threadIdx.x >> 6);
    const int lane = threadIdx.x & 63;
    const int n = gw >> 12, k = gw & 4095;
    const int base = n*4096;
    const int i0 = sidx[base + k];
    const int im = sidx[base + ((k + 4095) & 4095)];
    const int ip = sidx[base + ((k + 1) & 4095)];
    const float4* x0 = (const float4*)(X + ((size_t)base + i0)*256);
    const float4* xm = (const float4*)(X + ((size_t)base + im)*256);
    const float4* xp = (const float4*)(X + ((size_t)base + ip)*256);
    const float4* ir4 = (const float4*)(invr + n*256);
    float4 a = x0[lane], m_ = xm[lane], p_ = xp[lane], ir = ir4[lane];
    float ax = a.x*ir.x, ay = a.y*ir.y, az = a.z*ir.z, aw = a.w*ir.w;
    float p0 = ax*a.x + ay*a.y + az*a.z + aw*a.w;
    float p1 = ax*m_.x + ay*m_.y + az*m_.z + aw*m_.w;
    float p2 = ax*p_.x + ay*p_.y + az*p_.z + aw*p_.w;
    #pragma unroll
    for (int off = 32; off > 0; off >>= 1) {
        p0 += __shfl_xor(p0, off, 64);
        p1 += __shfl_xor(p1, off, 64);
        p2 += __shfl_xor(p2, off, 64);
    }
    if (lane == 0) {
        float m = fmaxf(p0, fmaxf(p1, p2));
        float bs = m + logf(expf(p0 - m) + expf(p1 - m) + expf(p2 - m));
        S0[gw] = p0; S1[gw] = p1; S2[gw] = p2; BS[gw] = bs;
    }
}

// Per-batch max & sum(exp) of bucket scores.
__global__ __launch_bounds__(256) void k_red(const float* __restrict__ BS,
                                             float* __restrict__ MX, float* __restrict__ Zs)
{
    __shared__ float red[256];
    const int n = blockIdx.x, tid = threadIdx.x;
    const float* b = BS + n*4096;
    float mx = -3.0e38f;
    for (int i = 0; i < 16; ++i) mx = fmaxf(mx, b[i*256 + tid]);
    red[tid] = mx; __syncthreads();
    for (int s = 128; s > 0; s >>= 1) { if (tid < s) red[tid] = fmaxf(red[tid], red[tid + s]); __syncthreads(); }
    float gmx = red[0];
    __syncthreads();
    float sum = 0.f;
    for (int i = 0; i < 16; ++i) sum += expf(b[i*256 + tid] - gmx);
    red[tid] = sum; __syncthreads();
    for (int s = 128; s > 0; s >>= 1) { if (tid < s) red[tid] += red[tid + s]; __syncthreads(); }
    if (tid == 0) { MX[n] = gmx; Zs[n] = red[0]; }
}

// One wave per original position p: gather ys rows, softmax-3 combine, global prob, blend.
__global__ __launch_bounds__(256) void k_final(
    const float* __restrict__ inp, const float* __restrict__ Y,
    const int* __restrict__ sidx, const int* __restrict__ us,
    const float* __restrict__ S0, const float* __restrict__ S1,
    const float* __restrict__ S2, const float* __restrict__ BS,
    const float* __restrict__ MX, const float* __restrict__ Zs,
    const float* __restrict__ alpha_p, float* __restrict__ outp)
{
    const int gw = blockIdx.x*4 + (threadIdx.x >> 6);
    const int lane = threadIdx.x & 63;
    const int n = gw >> 12, p = gw & 4095;
    const int base = n*4096;
    const int k = us[base + p];
    const int i0 = sidx[base + k];
    const int im = sidx[base + ((k + 4095) & 4095)];
    const int ip = sidx[base + ((k + 1) & 4095)];
    const int kk = base + k;
    float bs = BS[kk];
    float w0 = expf(S0[kk] - bs), w1 = expf(S1[kk] - bs), w2 = expf(S2[kk] - bs);
    float alpha = alpha_p[0];
    float coef = (1.0f - alpha) * expf(bs - MX[n]) / Zs[n];
    const float4* y0 = (const float4*)(Y + ((size_t)base + i0)*256);
    const float4* ym = (const float4*)(Y + ((size_t)base + im)*256);
    const float4* yp = (const float4*)(Y + ((size_t)base + ip)*256);
    const float4* iv = (const float4*)(inp + ((size_t)base + p)*256);
    float4 A = y0[lane], Bv = ym[lane], Cv = yp[lane], I = iv[lane];
    float4 o;
    o.x = alpha*I.x + coef*(w0*A.x + w1*Bv.x + w2*Cv.x);
    o.y = alpha*I.y + coef*(w0*A.y + w1*Bv.y + w2*Cv.y);
    o.z = alpha*I.z + coef*(w0*A.z + w1*Bv.z + w2*Cv.z);
    o.w = alpha*I.w + coef*(w0*A.w + w1*Bv.w + w2*Cv.w);
    ((float4*)(outp + ((size_t)base + p)*256))[lane] = o;
}

extern "C" void kernel_launch(void* const* d_in, const int* in_sizes, int n_in,
                              void* d_out, int out_size, void* d_ws, size_t ws_size,
                              hipStream_t stream)
{
    const float* inputs = (const float*)d_in[0];
    const float* Wx  = (const float*)d_in[1];
    const float* bx  = (const float*)d_in[2];
    const float* gx  = (const float*)d_in[3];
    const float* bex = (const float*)d_in[4];
    const float* Wy  = (const float*)d_in[5];
    const float* by  = (const float*)d_in[6];
    const float* gy  = (const float*)d_in[7];
    const float* bey = (const float*)d_in[8];
    const float* means = (const float*)d_in[9];
    const float* alpha = (const float*)d_in[10];

    if (ws_size < WS_NEED) return;  // loud failure (output stays poisoned)

    char* ws = (char*)d_ws;
    _Float16* WX2 = (_Float16*)(ws + B_WX2);
    _Float16* WY2 = (_Float16*)(ws + B_WY2);
    _Float16* M2  = (_Float16*)(ws + B_M2);
    float*  invr1 = (float*)(ws + B_INVR1);
    float*  invr2 = (float*)(ws + B_INVR2);
    float*  S0    = (float*)(ws + B_S0);
    float*  S1    = (float*)(ws + B_S1);
    float*  S2    = (float*)(ws + B_S2);
    float*  BSb   = (float*)(ws + B_BS);
    float*  MX    = (float*)(ws + B_MX);
    float*  Zs    = (float*)(ws + B_Z);
    double* r2    = (double*)(ws + B_R2);
    int*    codes = (int*)(ws + B_CODES);
    int*    sidx  = (int*)(ws + B_IDX);
    int*    us    = (int*)(ws + B_US);
    float*  XE    = (float*)(ws + B_XE);
    float*  YE    = (float*)(ws + B_YE);
    float*  outp  = (float*)d_out;

    hipMemsetAsync(r2, 0, 4096*8, stream);
    k_prep<<<512, 256, 0, stream>>>(Wx, Wy, means, WX2, WY2, M2);
    k_embed_mfma<<<2048, 256, 0, stream>>>(inputs, WX2, bx, gx, bex, XE, r2, 1);
    k_embed_mfma<<<2048, 256, 0, stream>>>(inputs, WY2, by, gy, bey, YE, r2, 0);
    k_finish<<<16, 256, 0, stream>>>(r2, invr1, invr2);
    k_dists_mfma<<<2048, 512, 0, stream>>>(XE, M2, invr1, codes);
    k_sort<<<16, 256, 0, stream>>>(codes, sidx, us);
    k_bs<<<16384, 256, 0, stream>>>(XE, invr2, sidx, S0, S1, S2, BSb);
    k_red<<<16, 256, 0, stream>>>(BSb, MX, Zs);
    k_final<<<16384, 256, 0, stream>>>(inputs, YE, sidx, us, S0, S1, S2, BSb, MX, Zs, alpha, outp);
}